// Round 1
// baseline (2035.288 us; speedup 1.0000x reference)
//
#include <hip/hip_runtime.h>
#include <math.h>

#define R_TOT 16384   // B*T
#define DIN   1024    // D
#define DC    256     // Dc
#define KCB   8192    // K codebook entries

// ws layout (float offsets)
#define WS_CN     0                         // code_norm 8192*256
#define WS_ZN     (WS_CN + KCB*DC)          // z_norm 16384*256
#define WS_C2     (WS_ZN + R_TOT*DC)        // |c|^2 per code, 8192
#define WS_CODES  (WS_C2 + KCB)             // argmin indices (int), 16384
#define WS_PART   (WS_CODES + R_TOT)        // loss partials, 512

// ---------------- Kernel 1: normalize codebook rows ----------------
__global__ __launch_bounds__(64) void k_codenorm(const float* __restrict__ cb,
                                                 float* __restrict__ cn,
                                                 float* __restrict__ c2) {
  int row = blockIdx.x;
  int lane = threadIdx.x;
  float4 v = reinterpret_cast<const float4*>(cb)[row*(DC/4) + lane];
  float s = v.x*v.x + v.y*v.y + v.z*v.z + v.w*v.w;
  #pragma unroll
  for (int m = 1; m < 64; m <<= 1) s += __shfl_xor(s, m);
  float inv = 1.0f / fmaxf(sqrtf(s), 1e-12f);
  float4 o = make_float4(v.x*inv, v.y*inv, v.z*inv, v.w*inv);
  reinterpret_cast<float4*>(cn)[row*(DC/4) + lane] = o;
  float s2 = o.x*o.x + o.y*o.y + o.z*o.z + o.w*o.w;
  #pragma unroll
  for (int m = 1; m < 64; m <<= 1) s2 += __shfl_xor(s2, m);
  if (lane == 0) c2[row] = s2;
}

// ---------------- Kernel 2: z_lin = z @ w_z^T, fused l2norm ----------------
// block: 64 rows x 256 cols (all cols -> can normalize in-kernel). 256 thr.
// thread: tx=tid&15 (cols tx+16j), ty=tid>>4 (rows ty+16i). acc[4][16].
__global__ __launch_bounds__(256) void k_zlin(const float* __restrict__ z,
                                              const float* __restrict__ wz,
                                              float* __restrict__ zn) {
  __shared__ float zs[32][65];    // k-major, 64 rows, odd stride
  __shared__ float wsh[32][258];  // k-major, 256 cols
  const int tid = threadIdx.x;
  const int tx = tid & 15;
  const int ty = tid >> 4;
  const int rb = blockIdx.x * 64;
  float acc[4][16];
  #pragma unroll
  for (int i = 0; i < 4; i++)
    #pragma unroll
    for (int j = 0; j < 16; j++) acc[i][j] = 0.f;

  for (int kb = 0; kb < DIN; kb += 32) {
    __syncthreads();
    #pragma unroll
    for (int q = 0; q < 2; q++) {
      int idx = tid + 256*q;
      int r = idx >> 3, f4 = idx & 7;
      float4 v = *reinterpret_cast<const float4*>(&z[(size_t)(rb + r)*DIN + kb + f4*4]);
      zs[f4*4+0][r] = v.x; zs[f4*4+1][r] = v.y; zs[f4*4+2][r] = v.z; zs[f4*4+3][r] = v.w;
    }
    #pragma unroll
    for (int q = 0; q < 8; q++) {
      int idx = tid + 256*q;
      int c = idx >> 3, f4 = idx & 7;
      float4 v = *reinterpret_cast<const float4*>(&wz[(size_t)c*DIN + kb + f4*4]);
      wsh[f4*4+0][c] = v.x; wsh[f4*4+1][c] = v.y; wsh[f4*4+2][c] = v.z; wsh[f4*4+3][c] = v.w;
    }
    __syncthreads();
    #pragma unroll
    for (int kk = 0; kk < 32; kk++) {
      float zv[4], wv[16];
      #pragma unroll
      for (int i = 0; i < 4; i++) zv[i] = zs[kk][ty + 16*i];
      #pragma unroll
      for (int j = 0; j < 16; j++) wv[j] = wsh[kk][tx + 16*j];
      #pragma unroll
      for (int i = 0; i < 4; i++)
        #pragma unroll
        for (int j = 0; j < 16; j++) acc[i][j] += zv[i] * wv[j];
    }
  }
  // fused row l2norm: threads sharing a row are the 16 lanes differing in tx
  #pragma unroll
  for (int i = 0; i < 4; i++) {
    float s = 0.f;
    #pragma unroll
    for (int j = 0; j < 16; j++) s += acc[i][j]*acc[i][j];
    #pragma unroll
    for (int m = 1; m < 16; m <<= 1) s += __shfl_xor(s, m);
    float inv = 1.0f / fmaxf(sqrtf(s), 1e-12f);
    int r = rb + ty + 16*i;
    #pragma unroll
    for (int j = 0; j < 16; j++)
      zn[(size_t)r*DC + tx + 16*j] = acc[i][j] * inv;
  }
}

// ---------------- Kernel 3: fused distance + argmin ----------------
// block: 32 rows, loops all 8192 codes in tiles of 256; 256 thr.
// thread: cx=tid&31 (codes cx+32j, j<8), ry=tid>>5 (rows ry+8i, i<4). acc[4][8].
// dist' = |c|^2 - 2*dot (row term constant per row -> same argmin).
__global__ __launch_bounds__(256) void k_argmin(const float* __restrict__ zn,
                                                const float* __restrict__ cn,
                                                const float* __restrict__ c2,
                                                int* __restrict__ codes_i,
                                                float* __restrict__ codes_f) {
  __shared__ float zt[256][33];   // k-major, 32 rows  (33792 B)
  __shared__ float cs[16][257];   // k-chunk 16 x 256 codes (16448 B)
  const int tid = threadIdx.x;
  const int cx = tid & 31;
  const int ry = tid >> 5;        // 0..7
  const int rb = blockIdx.x * 32;

  // stage z tile once (full Dc)
  #pragma unroll
  for (int q = 0; q < 8; q++) {
    int idx = tid + 256*q;        // 0..2047
    int r = idx >> 6, f4 = idx & 63;
    float4 v = *reinterpret_cast<const float4*>(&zn[(size_t)(rb + r)*DC + f4*4]);
    zt[f4*4+0][r] = v.x; zt[f4*4+1][r] = v.y; zt[f4*4+2][r] = v.z; zt[f4*4+3][r] = v.w;
  }

  float bestd[4]; int besti[4];
  #pragma unroll
  for (int i = 0; i < 4; i++) { bestd[i] = 3.4e38f; besti[i] = 0; }

  for (int cbx = 0; cbx < KCB; cbx += 256) {
    float acc[4][8];
    #pragma unroll
    for (int i = 0; i < 4; i++)
      #pragma unroll
      for (int j = 0; j < 8; j++) acc[i][j] = 0.f;

    for (int kb = 0; kb < DC; kb += 16) {
      __syncthreads();   // also covers zt staging before first use
      #pragma unroll
      for (int q = 0; q < 4; q++) {
        int idx = tid + 256*q;    // 0..1023
        int c = idx >> 2, f4 = idx & 3;
        float4 v = *reinterpret_cast<const float4*>(&cn[(size_t)(cbx + c)*DC + kb + f4*4]);
        cs[f4*4+0][c] = v.x; cs[f4*4+1][c] = v.y; cs[f4*4+2][c] = v.z; cs[f4*4+3][c] = v.w;
      }
      __syncthreads();
      #pragma unroll
      for (int kk = 0; kk < 16; kk++) {
        float zv[4], cv[8];
        #pragma unroll
        for (int i = 0; i < 4; i++) zv[i] = zt[kb + kk][ry + 8*i];
        #pragma unroll
        for (int j = 0; j < 8; j++) cv[j] = cs[kk][cx + 32*j];
        #pragma unroll
        for (int i = 0; i < 4; i++)
          #pragma unroll
          for (int j = 0; j < 8; j++) acc[i][j] += zv[i] * cv[j];
      }
    }
    // running argmin update (ascending code index -> strict < keeps first)
    #pragma unroll
    for (int j = 0; j < 8; j++) {
      int c = cbx + cx + 32*j;
      float cc = c2[c];
      #pragma unroll
      for (int i = 0; i < 4; i++) {
        float d = cc - 2.0f*acc[i][j];
        if (d < bestd[i]) { bestd[i] = d; besti[i] = c; }
      }
    }
  }
  // cross-lane reduce over cx (low 5 bits), tie -> lower index
  #pragma unroll
  for (int i = 0; i < 4; i++) {
    float d = bestd[i]; int bi = besti[i];
    #pragma unroll
    for (int m = 1; m < 32; m <<= 1) {
      float od = __shfl_xor(d, m);
      int   oi = __shfl_xor(bi, m);
      if (od < d || (od == d && oi < bi)) { d = od; bi = oi; }
    }
    if (cx == 0) {
      int r = rb + ry + 8*i;
      codes_i[r] = bi;
      codes_f[r] = (float)bi;
    }
  }
}

// ---------------- Kernel 4: q = gather(code_norm) @ w_q^T ----------------
// block: 32 rows x 128 d-cols; grid (512, 8); 256 thr; acc[4][4].
__global__ __launch_bounds__(256) void k_qgemm(const int* __restrict__ codes_i,
                                               const float* __restrict__ cn,
                                               const float* __restrict__ wq,
                                               float* __restrict__ qout) {
  __shared__ float At[64][33];    // k-chunk 64 x 32 rows
  __shared__ float Bt[64][129];   // k-chunk 64 x 128 cols
  const int tid = threadIdx.x;
  const int cx = tid & 31;
  const int ry = tid >> 5;
  const int rb = blockIdx.x * 32;
  const int db = blockIdx.y * 128;
  float acc[4][4];
  #pragma unroll
  for (int i = 0; i < 4; i++)
    #pragma unroll
    for (int j = 0; j < 4; j++) acc[i][j] = 0.f;

  for (int kb = 0; kb < DC; kb += 64) {
    __syncthreads();
    #pragma unroll
    for (int q = 0; q < 2; q++) {
      int idx = tid + 256*q;      // 0..511
      int r = idx >> 4, f4 = idx & 15;
      int code = codes_i[rb + r];
      float4 v = *reinterpret_cast<const float4*>(&cn[(size_t)code*DC + kb + f4*4]);
      At[f4*4+0][r] = v.x; At[f4*4+1][r] = v.y; At[f4*4+2][r] = v.z; At[f4*4+3][r] = v.w;
    }
    #pragma unroll
    for (int q = 0; q < 8; q++) {
      int idx = tid + 256*q;      // 0..2047
      int d = idx >> 4, f4 = idx & 15;
      float4 v = *reinterpret_cast<const float4*>(&wq[(size_t)(db + d)*DC + kb + f4*4]);
      Bt[f4*4+0][d] = v.x; Bt[f4*4+1][d] = v.y; Bt[f4*4+2][d] = v.z; Bt[f4*4+3][d] = v.w;
    }
    __syncthreads();
    #pragma unroll
    for (int kk = 0; kk < 64; kk++) {
      float av[4], bv[4];
      #pragma unroll
      for (int i = 0; i < 4; i++) av[i] = At[kk][ry + 8*i];
      #pragma unroll
      for (int j = 0; j < 4; j++) bv[j] = Bt[kk][cx + 32*j];
      #pragma unroll
      for (int i = 0; i < 4; i++)
        #pragma unroll
        for (int j = 0; j < 4; j++) acc[i][j] += av[i] * bv[j];
    }
  }
  #pragma unroll
  for (int i = 0; i < 4; i++)
    #pragma unroll
    for (int j = 0; j < 4; j++)
      qout[(size_t)(rb + ry + 8*i)*DIN + db + cx + 32*j] = acc[i][j];
}

// ---------------- Kernel 5/6: quantize loss ----------------
__global__ __launch_bounds__(256) void k_losspart(const float* __restrict__ zn,
                                                  const float* __restrict__ cn,
                                                  const int* __restrict__ codes_i,
                                                  float* __restrict__ part) {
  const int tid = threadIdx.x;
  const size_t base = (size_t)blockIdx.x * 8192;
  float s = 0.f;
  #pragma unroll
  for (int k = 0; k < 32; k++) {
    size_t e = base + (size_t)k*256 + tid;
    int r = (int)(e >> 8);
    int c = (int)(e & 255);
    float d = cn[(size_t)codes_i[r]*DC + c] - zn[e];
    s += d * d;
  }
  #pragma unroll
  for (int m = 1; m < 64; m <<= 1) s += __shfl_xor(s, m);
  __shared__ float red[4];
  if ((tid & 63) == 0) red[tid >> 6] = s;
  __syncthreads();
  if (tid == 0) part[blockIdx.x] = (red[0] + red[1]) + (red[2] + red[3]);
}

__global__ __launch_bounds__(256) void k_lossfinal(const float* __restrict__ part,
                                                   float* __restrict__ loss_out) {
  const int tid = threadIdx.x;
  float s = part[tid] + part[tid + 256];
  #pragma unroll
  for (int m = 1; m < 64; m <<= 1) s += __shfl_xor(s, m);
  __shared__ float red[4];
  if ((tid & 63) == 0) red[tid >> 6] = s;
  __syncthreads();
  if (tid == 0) {
    float tot = (red[0] + red[1]) + (red[2] + red[3]);
    loss_out[0] = tot * 1.25f / 4194304.0f;   // 1.25 * mean over 16384*256
  }
}

extern "C" void kernel_launch(void* const* d_in, const int* in_sizes, int n_in,
                              void* d_out, int out_size, void* d_ws, size_t ws_size,
                              hipStream_t stream) {
  const float* z  = (const float*)d_in[0];
  const float* cb = (const float*)d_in[1];
  const float* wz = (const float*)d_in[2];
  const float* wq = (const float*)d_in[3];

  float* out = (float*)d_out;
  float* q_out   = out;                           // 16384*1024
  float* codes_f = out + (size_t)R_TOT*DIN;       // 16384
  float* loss_o  = codes_f + R_TOT;               // 1

  float* ws = (float*)d_ws;
  float* cn = ws + WS_CN;
  float* zn = ws + WS_ZN;
  float* c2 = ws + WS_C2;
  int*   ci = (int*)(ws + WS_CODES);
  float* pt = ws + WS_PART;

  hipLaunchKernelGGL(k_codenorm, dim3(KCB), dim3(64), 0, stream, cb, cn, c2);
  hipLaunchKernelGGL(k_zlin, dim3(R_TOT/64), dim3(256), 0, stream, z, wz, zn);
  hipLaunchKernelGGL(k_argmin, dim3(R_TOT/32), dim3(256), 0, stream, zn, cn, c2, ci, codes_f);
  hipLaunchKernelGGL(k_qgemm, dim3(R_TOT/32, DIN/128), dim3(256), 0, stream, ci, cn, wq, q_out);
  hipLaunchKernelGGL(k_losspart, dim3(512), dim3(256), 0, stream, zn, cn, ci, pt);
  hipLaunchKernelGGL(k_lossfinal, dim3(1), dim3(256), 0, stream, pt, loss_o);
}

// Round 2
// 808.162 us; speedup vs baseline: 2.5184x; 2.5184x over previous
//
#include <hip/hip_runtime.h>
#include <hip/hip_bf16.h>
#include <math.h>

#define R_TOT 16384   // B*T
#define DIN   1024    // D
#define DC    256     // Dc
#define KCB   8192    // K codebook entries

typedef __attribute__((ext_vector_type(8))) short bf16x8;
typedef __attribute__((ext_vector_type(4))) float f32x4;

// ws layout (float offsets)
#define WS_CN    0u         // code_norm f32           8192*256  = 2097152
#define WS_ZN    2097152u   // z_norm f32             16384*256  = 4194304
#define WS_C2    6291456u   // |c|^2 f32                          8192
#define WS_CODES 6299648u   // codes int                          16384
#define WS_PART  6316032u   // loss partials                      512
#define WS_CBF   6316544u   // code_norm bf16 (2097152 bf16 = 1048576 f)
#define WS_ZBF   7365120u   // z_norm bf16    (4194304 bf16 = 2097152 f)
#define WS_RBP   9462272u   // rowbest partials 4*16384           65536
#define WS_RB    9527808u   // rowbest combined                   16384
#define WS_KEYS  9544192u   // u64 keys 16384 (= 32768 f)

__device__ __forceinline__ unsigned short f2bf(float x) {
  __hip_bfloat16 h = __float2bfloat16(x);
  unsigned short u; __builtin_memcpy(&u, &h, 2); return u;
}

__device__ __forceinline__ void gload_lds16(const void* g, void* l) {
  __builtin_amdgcn_global_load_lds(
      (const __attribute__((address_space(1))) unsigned int*)g,
      (__attribute__((address_space(3))) unsigned int*)l, 16, 0, 0);
}

// ---------------- Kernel 1: normalize codebook rows (+ bf16 copy) ----------------
__global__ __launch_bounds__(64) void k_codenorm(const float* __restrict__ cb,
                                                 float* __restrict__ cn,
                                                 float* __restrict__ c2,
                                                 unsigned short* __restrict__ cbf) {
  int row = blockIdx.x;
  int lane = threadIdx.x;
  float4 v = reinterpret_cast<const float4*>(cb)[row*(DC/4) + lane];
  float s = v.x*v.x + v.y*v.y + v.z*v.z + v.w*v.w;
  #pragma unroll
  for (int m = 1; m < 64; m <<= 1) s += __shfl_xor(s, m);
  float inv = 1.0f / fmaxf(sqrtf(s), 1e-12f);
  float4 o = make_float4(v.x*inv, v.y*inv, v.z*inv, v.w*inv);
  reinterpret_cast<float4*>(cn)[row*(DC/4) + lane] = o;
  ushort4 pk;
  pk.x = f2bf(o.x); pk.y = f2bf(o.y); pk.z = f2bf(o.z); pk.w = f2bf(o.w);
  reinterpret_cast<ushort4*>(cbf)[row*(DC/4) + lane] = pk;
  float s2 = o.x*o.x + o.y*o.y + o.z*o.z + o.w*o.w;
  #pragma unroll
  for (int m = 1; m < 64; m <<= 1) s2 += __shfl_xor(s2, m);
  if (lane == 0) c2[row] = s2;
}

// ---------------- Kernel 2: z_lin = z @ w_z^T, fused l2norm (+ bf16 copy) --------
__global__ __launch_bounds__(256) void k_zlin(const float* __restrict__ z,
                                              const float* __restrict__ wz,
                                              float* __restrict__ zn,
                                              unsigned short* __restrict__ zbf) {
  __shared__ float zs[32][65];
  __shared__ float wsh[32][258];
  const int tid = threadIdx.x;
  const int tx = tid & 15;
  const int ty = tid >> 4;
  const int rb = blockIdx.x * 64;
  float acc[4][16];
  #pragma unroll
  for (int i = 0; i < 4; i++)
    #pragma unroll
    for (int j = 0; j < 16; j++) acc[i][j] = 0.f;

  for (int kb = 0; kb < DIN; kb += 32) {
    __syncthreads();
    #pragma unroll
    for (int q = 0; q < 2; q++) {
      int idx = tid + 256*q;
      int r = idx >> 3, f4 = idx & 7;
      float4 v = *reinterpret_cast<const float4*>(&z[(size_t)(rb + r)*DIN + kb + f4*4]);
      zs[f4*4+0][r] = v.x; zs[f4*4+1][r] = v.y; zs[f4*4+2][r] = v.z; zs[f4*4+3][r] = v.w;
    }
    #pragma unroll
    for (int q = 0; q < 8; q++) {
      int idx = tid + 256*q;
      int c = idx >> 3, f4 = idx & 7;
      float4 v = *reinterpret_cast<const float4*>(&wz[(size_t)c*DIN + kb + f4*4]);
      wsh[f4*4+0][c] = v.x; wsh[f4*4+1][c] = v.y; wsh[f4*4+2][c] = v.z; wsh[f4*4+3][c] = v.w;
    }
    __syncthreads();
    #pragma unroll
    for (int kk = 0; kk < 32; kk++) {
      float zv[4], wv[16];
      #pragma unroll
      for (int i = 0; i < 4; i++) zv[i] = zs[kk][ty + 16*i];
      #pragma unroll
      for (int j = 0; j < 16; j++) wv[j] = wsh[kk][tx + 16*j];
      #pragma unroll
      for (int i = 0; i < 4; i++)
        #pragma unroll
        for (int j = 0; j < 16; j++) acc[i][j] += zv[i] * wv[j];
    }
  }
  #pragma unroll
  for (int i = 0; i < 4; i++) {
    float s = 0.f;
    #pragma unroll
    for (int j = 0; j < 16; j++) s += acc[i][j]*acc[i][j];
    #pragma unroll
    for (int m = 1; m < 16; m <<= 1) s += __shfl_xor(s, m);
    float inv = 1.0f / fmaxf(sqrtf(s), 1e-12f);
    int r = rb + ty + 16*i;
    #pragma unroll
    for (int j = 0; j < 16; j++) {
      float val = acc[i][j] * inv;
      zn[(size_t)r*DC + tx + 16*j] = val;
      zbf[(size_t)r*DC + tx + 16*j] = f2bf(val);
    }
  }
}

// ---------------- Kernel 3: MFMA distance passes ----------------
// PASS 1: per-row max approx dot (bf16 MFMA), partials per code-split.
// PASS 2: recompute identical approx dots; exact-f32 refine for candidates
//         within margin; atomicMin packed (ordered-dist, idx) key.
// Block: 256 thr = 4 waves x 32 rows = 128 rows; grid (128 rowblocks, 4 splits).
template<int PASS>
__global__ __launch_bounds__(256) void k_dist(
    const unsigned short* __restrict__ zbf, const unsigned short* __restrict__ cbf,
    const float* __restrict__ zn, const float* __restrict__ cn,
    const float* __restrict__ c2, const float* __restrict__ rowbest,
    float* __restrict__ rbp, unsigned long long* __restrict__ keys) {
  __shared__ unsigned short Bs[64*256];   // 32 KB, chunk-XOR swizzled
  const int tid  = threadIdx.x;
  const int lane = tid & 63;
  const int wv   = tid >> 6;
  const int lo   = lane & 15, hi = lane >> 4;
  const int rb   = blockIdx.x * 128 + wv * 32;
  const int cb0  = blockIdx.y * (KCB/4);

  // A fragments: 32 rows x 256 k in regs. row = lane&15, k = (lane>>4)*8 + e.
  bf16x8 a[2][8];
  #pragma unroll
  for (int s = 0; s < 2; s++)
    #pragma unroll
    for (int ks = 0; ks < 8; ks++)
      a[s][ks] = *reinterpret_cast<const bf16x8*>(
          &zbf[(size_t)(rb + s*16 + lo)*DC + ks*32 + hi*8]);

  float trk[2][4];
  #pragma unroll
  for (int s = 0; s < 2; s++)
    #pragma unroll
    for (int r = 0; r < 4; r++) {
      if (PASS == 1) trk[s][r] = -1e30f;
      else           trk[s][r] = rowbest[rb + s*16 + hi*4 + r] - 0.01f;
    }

  // staging source offsets (chunk-XOR pre-swizzled global, linear LDS dest)
  size_t soff[8];
  #pragma unroll
  for (int i = 0; i < 8; i++) {
    int code = (wv*8 + i)*2 + (lane >> 5);
    int chg  = (lane & 31) ^ (code & 7);
    soff[i]  = (size_t)code*512 + (size_t)chg*16;
  }

  for (int t = 0; t < 32; t++) {
    const int cbx = cb0 + t*64;
    __syncthreads();
    #pragma unroll
    for (int i = 0; i < 8; i++) {
      const char* src = (const char*)cbf + (size_t)cbx*512 + soff[i];
      char* dst = (char*)Bs + (wv*8 + i)*1024;
      gload_lds16(src, dst);
    }
    asm volatile("s_waitcnt vmcnt(0)" ::: "memory");
    __syncthreads();

    f32x4 acc[2][4];
    #pragma unroll
    for (int s = 0; s < 2; s++)
      #pragma unroll
      for (int cs = 0; cs < 4; cs++)
        acc[s][cs] = (f32x4){0.f, 0.f, 0.f, 0.f};

    #pragma unroll
    for (int ks = 0; ks < 8; ks++) {
      const int chl = (ks*4 + hi) ^ (lo & 7);
      #pragma unroll
      for (int cs = 0; cs < 4; cs++) {
        bf16x8 b = *reinterpret_cast<const bf16x8*>(&Bs[(cs*16 + lo)*256 + chl*8]);
        acc[0][cs] = __builtin_amdgcn_mfma_f32_16x16x32_bf16(a[0][ks], b, acc[0][cs], 0, 0, 0);
        acc[1][cs] = __builtin_amdgcn_mfma_f32_16x16x32_bf16(a[1][ks], b, acc[1][cs], 0, 0, 0);
      }
    }

    if (PASS == 1) {
      #pragma unroll
      for (int s = 0; s < 2; s++)
        #pragma unroll
        for (int r = 0; r < 4; r++) {
          float mx = fmaxf(fmaxf(acc[s][0][r], acc[s][1][r]),
                           fmaxf(acc[s][2][r], acc[s][3][r]));
          trk[s][r] = fmaxf(trk[s][r], mx);
        }
    } else {
      #pragma unroll
      for (int s = 0; s < 2; s++)
        #pragma unroll
        for (int r = 0; r < 4; r++) {
          float mx = fmaxf(fmaxf(acc[s][0][r], acc[s][1][r]),
                           fmaxf(acc[s][2][r], acc[s][3][r]));
          if (mx >= trk[s][r]) {
            const int row = rb + s*16 + hi*4 + r;
            #pragma unroll
            for (int cs = 0; cs < 4; cs++) {
              if (acc[s][cs][r] >= trk[s][r]) {
                const int code = cbx + cs*16 + lo;
                float dot = 0.f;
                const float4* zr = reinterpret_cast<const float4*>(zn + (size_t)row*DC);
                const float4* cr = reinterpret_cast<const float4*>(cn + (size_t)code*DC);
                #pragma unroll 4
                for (int q = 0; q < 64; q++) {
                  float4 x = zr[q], y = cr[q];
                  dot += x.x*y.x; dot += x.y*y.y; dot += x.z*y.z; dot += x.w*y.w;
                }
                float e = c2[code] - 2.f*dot;
                unsigned ue = __float_as_uint(e);
                ue = (ue & 0x80000000u) ? ~ue : (ue | 0x80000000u);
                unsigned long long key = ((unsigned long long)ue << 32) | (unsigned)code;
                atomicMin(&keys[row], key);
              }
            }
          }
        }
    }
  }

  if (PASS == 1) {
    #pragma unroll
    for (int s = 0; s < 2; s++)
      #pragma unroll
      for (int r = 0; r < 4; r++) {
        float m = trk[s][r];
        #pragma unroll
        for (int msk = 1; msk < 16; msk <<= 1) m = fmaxf(m, __shfl_xor(m, msk));
        if (lo == 0) rbp[(size_t)blockIdx.y*R_TOT + rb + s*16 + hi*4 + r] = m;
      }
  }
}

__global__ __launch_bounds__(256) void k_combine(const float* __restrict__ rbp,
                                                 float* __restrict__ rowbest) {
  int r = blockIdx.x*256 + threadIdx.x;
  rowbest[r] = fmaxf(fmaxf(rbp[r], rbp[R_TOT + r]),
                     fmaxf(rbp[2*R_TOT + r], rbp[3*R_TOT + r]));
}

__global__ __launch_bounds__(256) void k_final(const unsigned long long* __restrict__ keys,
                                               int* __restrict__ ci,
                                               float* __restrict__ cf) {
  int r = blockIdx.x*256 + threadIdx.x;
  int idx = (int)(keys[r] & 0xFFFFFFFFull);
  ci[r] = idx;
  cf[r] = (float)idx;
}

// ---------------- Kernel 4: q = gather(code_norm) @ w_q^T ----------------
__global__ __launch_bounds__(256) void k_qgemm(const int* __restrict__ codes_i,
                                               const float* __restrict__ cn,
                                               const float* __restrict__ wq,
                                               float* __restrict__ qout) {
  __shared__ float At[64][33];
  __shared__ float Bt[64][129];
  const int tid = threadIdx.x;
  const int cx = tid & 31;
  const int ry = tid >> 5;
  const int rb = blockIdx.x * 32;
  const int db = blockIdx.y * 128;
  float acc[4][4];
  #pragma unroll
  for (int i = 0; i < 4; i++)
    #pragma unroll
    for (int j = 0; j < 4; j++) acc[i][j] = 0.f;

  for (int kb = 0; kb < DC; kb += 64) {
    __syncthreads();
    #pragma unroll
    for (int q = 0; q < 2; q++) {
      int idx = tid + 256*q;
      int r = idx >> 4, f4 = idx & 15;
      int code = codes_i[rb + r];
      float4 v = *reinterpret_cast<const float4*>(&cn[(size_t)code*DC + kb + f4*4]);
      At[f4*4+0][r] = v.x; At[f4*4+1][r] = v.y; At[f4*4+2][r] = v.z; At[f4*4+3][r] = v.w;
    }
    #pragma unroll
    for (int q = 0; q < 8; q++) {
      int idx = tid + 256*q;
      int d = idx >> 4, f4 = idx & 15;
      float4 v = *reinterpret_cast<const float4*>(&wq[(size_t)(db + d)*DC + kb + f4*4]);
      Bt[f4*4+0][d] = v.x; Bt[f4*4+1][d] = v.y; Bt[f4*4+2][d] = v.z; Bt[f4*4+3][d] = v.w;
    }
    __syncthreads();
    #pragma unroll
    for (int kk = 0; kk < 64; kk++) {
      float av[4], bv[4];
      #pragma unroll
      for (int i = 0; i < 4; i++) av[i] = At[kk][ry + 8*i];
      #pragma unroll
      for (int j = 0; j < 4; j++) bv[j] = Bt[kk][cx + 32*j];
      #pragma unroll
      for (int i = 0; i < 4; i++)
        #pragma unroll
        for (int j = 0; j < 4; j++) acc[i][j] += av[i] * bv[j];
    }
  }
  #pragma unroll
  for (int i = 0; i < 4; i++)
    #pragma unroll
    for (int j = 0; j < 4; j++)
      qout[(size_t)(rb + ry + 8*i)*DIN + db + cx + 32*j] = acc[i][j];
}

// ---------------- Kernel 5/6: quantize loss ----------------
__global__ __launch_bounds__(256) void k_losspart(const float* __restrict__ zn,
                                                  const float* __restrict__ cn,
                                                  const int* __restrict__ codes_i,
                                                  float* __restrict__ part) {
  const int tid = threadIdx.x;
  const size_t base = (size_t)blockIdx.x * 8192;
  float s = 0.f;
  #pragma unroll
  for (int k = 0; k < 32; k++) {
    size_t e = base + (size_t)k*256 + tid;
    int r = (int)(e >> 8);
    int c = (int)(e & 255);
    float d = cn[(size_t)codes_i[r]*DC + c] - zn[e];
    s += d * d;
  }
  #pragma unroll
  for (int m = 1; m < 64; m <<= 1) s += __shfl_xor(s, m);
  __shared__ float red[4];
  if ((tid & 63) == 0) red[tid >> 6] = s;
  __syncthreads();
  if (tid == 0) part[blockIdx.x] = (red[0] + red[1]) + (red[2] + red[3]);
}

__global__ __launch_bounds__(256) void k_lossfinal(const float* __restrict__ part,
                                                   float* __restrict__ loss_out) {
  const int tid = threadIdx.x;
  float s = part[tid] + part[tid + 256];
  #pragma unroll
  for (int m = 1; m < 64; m <<= 1) s += __shfl_xor(s, m);
  __shared__ float red[4];
  if ((tid & 63) == 0) red[tid >> 6] = s;
  __syncthreads();
  if (tid == 0) {
    float tot = (red[0] + red[1]) + (red[2] + red[3]);
    loss_out[0] = tot * 1.25f / 4194304.0f;
  }
}

extern "C" void kernel_launch(void* const* d_in, const int* in_sizes, int n_in,
                              void* d_out, int out_size, void* d_ws, size_t ws_size,
                              hipStream_t stream) {
  const float* z  = (const float*)d_in[0];
  const float* cb = (const float*)d_in[1];
  const float* wz = (const float*)d_in[2];
  const float* wq = (const float*)d_in[3];

  float* out = (float*)d_out;
  float* q_out   = out;
  float* codes_f = out + (size_t)R_TOT*DIN;
  float* loss_o  = codes_f + R_TOT;

  float* ws = (float*)d_ws;
  float* cn = ws + WS_CN;
  float* zn = ws + WS_ZN;
  float* c2 = ws + WS_C2;
  int*   ci = (int*)(ws + WS_CODES);
  float* pt = ws + WS_PART;
  unsigned short* cbf = (unsigned short*)(ws + WS_CBF);
  unsigned short* zbf = (unsigned short*)(ws + WS_ZBF);
  float* rbp = ws + WS_RBP;
  float* rb  = ws + WS_RB;
  unsigned long long* keys = (unsigned long long*)(ws + WS_KEYS);

  hipMemsetAsync(keys, 0xFF, (size_t)R_TOT*sizeof(unsigned long long), stream);
  hipLaunchKernelGGL(k_codenorm, dim3(KCB), dim3(64), 0, stream, cb, cn, c2, cbf);
  hipLaunchKernelGGL(k_zlin, dim3(R_TOT/64), dim3(256), 0, stream, z, wz, zn, zbf);
  hipLaunchKernelGGL((k_dist<1>), dim3(R_TOT/128, 4), dim3(256), 0, stream,
                     zbf, cbf, zn, cn, c2, rb, rbp, keys);
  hipLaunchKernelGGL(k_combine, dim3(R_TOT/256), dim3(256), 0, stream, rbp, rb);
  hipLaunchKernelGGL((k_dist<2>), dim3(R_TOT/128, 4), dim3(256), 0, stream,
                     zbf, cbf, zn, cn, c2, rb, rbp, keys);
  hipLaunchKernelGGL(k_final, dim3(R_TOT/256), dim3(256), 0, stream, keys, ci, codes_f);
  hipLaunchKernelGGL(k_qgemm, dim3(R_TOT/32, DIN/128), dim3(256), 0, stream, ci, cn, wq, q_out);
  hipLaunchKernelGGL(k_losspart, dim3(512), dim3(256), 0, stream, zn, cn, ci, pt);
  hipLaunchKernelGGL(k_lossfinal, dim3(1), dim3(256), 0, stream, pt, loss_o);
}

// Round 3
// 487.355 us; speedup vs baseline: 4.1762x; 1.6583x over previous
//
#include <hip/hip_runtime.h>
#include <hip/hip_bf16.h>
#include <math.h>

#define R_TOT 16384   // B*T
#define DIN   1024    // D
#define DC    256     // Dc
#define KCB   8192    // K codebook entries
#define DSPLIT 8

typedef __attribute__((ext_vector_type(8))) short bf16x8;
typedef __attribute__((ext_vector_type(4))) float f32x4;

// ws layout (float offsets)
#define WS_CN    0u          // code_norm f32 8192*256
#define WS_ZN    2097152u    // z_norm f32 16384*256 (zlin written here, normed in place)
#define WS_C2    6291456u    // |c|^2
#define WS_CODES 6299648u    // codes int
#define WS_PART  6316032u    // loss partials 512
#define WS_CBF   6316544u    // code_norm bf16
#define WS_ZBF   7365120u    // z_norm bf16
#define WS_RBP   9462272u    // rowbest partials 8*16384
#define WS_RB    9593344u    // rowbest combined 16384
#define WS_KEYS  9609728u    // u64 keys 16384 (32768 f)
#define WS_WH    9642496u    // w_z hi bf16 256*1024 (131072 f)
#define WS_WL    9773568u    // w_z lo bf16
#define WS_WQB   9904640u    // w_q bf16 1024*256

__device__ __forceinline__ unsigned short f2bf(float x) {
  __hip_bfloat16 h = __float2bfloat16(x);
  unsigned short u; __builtin_memcpy(&u, &h, 2); return u;
}
__device__ __forceinline__ float bf2f(unsigned short u) {
  return __uint_as_float(((unsigned)u) << 16);
}
__device__ __forceinline__ void gload_lds16(const void* g, void* l) {
  __builtin_amdgcn_global_load_lds(
      (const __attribute__((address_space(1))) unsigned int*)g,
      (__attribute__((address_space(3))) unsigned int*)l, 16, 0, 0);
}

// ---------------- Kernel 1: normalize codebook rows (+ bf16 copy) ----------------
__global__ __launch_bounds__(64) void k_codenorm(const float* __restrict__ cb,
                                                 float* __restrict__ cn,
                                                 float* __restrict__ c2,
                                                 unsigned short* __restrict__ cbf) {
  int row = blockIdx.x;
  int lane = threadIdx.x;
  float4 v = reinterpret_cast<const float4*>(cb)[row*(DC/4) + lane];
  float s = v.x*v.x + v.y*v.y + v.z*v.z + v.w*v.w;
  #pragma unroll
  for (int m = 1; m < 64; m <<= 1) s += __shfl_xor(s, m);
  float inv = 1.0f / fmaxf(sqrtf(s), 1e-12f);
  float4 o = make_float4(v.x*inv, v.y*inv, v.z*inv, v.w*inv);
  reinterpret_cast<float4*>(cn)[row*(DC/4) + lane] = o;
  ushort4 pk;
  pk.x = f2bf(o.x); pk.y = f2bf(o.y); pk.z = f2bf(o.z); pk.w = f2bf(o.w);
  reinterpret_cast<ushort4*>(cbf)[row*(DC/4) + lane] = pk;
  float s2 = o.x*o.x + o.y*o.y + o.z*o.z + o.w*o.w;
  #pragma unroll
  for (int m = 1; m < 64; m <<= 1) s2 += __shfl_xor(s2, m);
  if (lane == 0) c2[row] = s2;
}

// ---------------- Kernel 1b: weight prep (wz hi/lo split, wq bf16) ----------------
__global__ __launch_bounds__(256) void k_wprep(const float* __restrict__ wz,
                                               const float* __restrict__ wq,
                                               unsigned short* __restrict__ wh,
                                               unsigned short* __restrict__ wl,
                                               unsigned short* __restrict__ wqb) {
  int i = blockIdx.x*256 + threadIdx.x;   // 0..262143
  float w = wz[i];
  unsigned short h = f2bf(w);
  wh[i] = h;
  wl[i] = f2bf(w - bf2f(h));
  wqb[i] = f2bf(wq[i]);
}

// ---------------- Kernel 2: z_lin = z @ w_z^T via bf16x4 MFMA ----------------
// block 512 thr = 8 waves (2 row-waves x 4 col-waves); block tile 64 rows x 256 cols.
// grid 256. K=1024 in 16 tiles of 64. A staged f32 (swizzled), split hi/lo in-reg.
__global__ __launch_bounds__(512, 2) void k_zlin2(const float* __restrict__ z,
                                                  const unsigned short* __restrict__ wh,
                                                  const unsigned short* __restrict__ wl,
                                                  float* __restrict__ zlin) {
  __shared__ float As[64*64];              // 16 KB, [row][64k f32] chunk^(row&15)
  __shared__ unsigned short WHs[256*64];   // 32 KB, [col][64k bf16] chunk^(col&7)
  __shared__ unsigned short WLs[256*64];   // 32 KB
  const int tid = threadIdx.x;
  const int lane = tid & 63;
  const int wv = tid >> 6;        // 0..7
  const int wc = wv & 3;          // col-wave
  const int wr = wv >> 2;         // row-wave
  const int lo = lane & 15, hi = lane >> 4;
  const int rb = blockIdx.x * 64;

  f32x4 acc[2][4];
  #pragma unroll
  for (int m = 0; m < 2; m++)
    #pragma unroll
    for (int cs = 0; cs < 4; cs++) acc[m][cs] = (f32x4){0.f,0.f,0.f,0.f};

  // staging source sub-offsets
  int rowA[2], chA[2];
  #pragma unroll
  for (int i = 0; i < 2; i++) {
    int w = wv*2 + i;
    rowA[i] = w*4 + (lane >> 4);               // 0..63
    chA[i]  = (lane & 15) ^ (rowA[i] & 15);
  }
  int colW[4], chW[4];
  #pragma unroll
  for (int i = 0; i < 4; i++) {
    int w = wv*4 + i;
    colW[i] = w*8 + (lane >> 3);               // 0..255
    chW[i]  = (lane & 7) ^ (colW[i] & 7);
  }

  for (int kb = 0; kb < DIN; kb += 64) {
    __syncthreads();
    #pragma unroll
    for (int i = 0; i < 2; i++) {
      const char* src = (const char*)z + ((size_t)(rb + rowA[i])*DIN + kb)*4 + chA[i]*16;
      gload_lds16(src, (char*)As + (wv*2 + i)*1024);
    }
    #pragma unroll
    for (int i = 0; i < 4; i++) {
      size_t rowoff = ((size_t)colW[i]*DIN + kb)*2;
      gload_lds16((const char*)wh + rowoff + chW[i]*16, (char*)WHs + (wv*4 + i)*1024);
      gload_lds16((const char*)wl + rowoff + chW[i]*16, (char*)WLs + (wv*4 + i)*1024);
    }
    asm volatile("s_waitcnt vmcnt(0)" ::: "memory");
    __syncthreads();

    // cache B fragments
    bf16x8 Bh[4][2], Bl[4][2];
    #pragma unroll
    for (int cs = 0; cs < 4; cs++)
      #pragma unroll
      for (int ks = 0; ks < 2; ks++) {
        int col = wc*64 + cs*16 + lo;
        int chl = (ks*4 + hi) ^ (lo & 7);
        Bh[cs][ks] = *reinterpret_cast<const bf16x8*>(&WHs[col*64 + chl*8]);
        Bl[cs][ks] = *reinterpret_cast<const bf16x8*>(&WLs[col*64 + chl*8]);
      }
    #pragma unroll
    for (int m = 0; m < 2; m++) {
      #pragma unroll
      for (int ks = 0; ks < 2; ks++) {
        int row = wr*32 + m*16 + lo;
        int c0 = ks*8 + hi*2;
        float4 v0 = *reinterpret_cast<const float4*>(&As[row*64 + ((c0  )^lo)*4]);
        float4 v1 = *reinterpret_cast<const float4*>(&As[row*64 + ((c0+1)^lo)*4]);
        float f[8] = {v0.x,v0.y,v0.z,v0.w,v1.x,v1.y,v1.z,v1.w};
        bf16x8 ah, al;
        #pragma unroll
        for (int e = 0; e < 8; e++) {
          unsigned short he = f2bf(f[e]);
          ah[e] = (short)he;
          al[e] = (short)f2bf(f[e] - bf2f(he));
        }
        #pragma unroll
        for (int cs = 0; cs < 4; cs++) {
          acc[m][cs] = __builtin_amdgcn_mfma_f32_16x16x32_bf16(ah, Bh[cs][ks], acc[m][cs], 0,0,0);
          acc[m][cs] = __builtin_amdgcn_mfma_f32_16x16x32_bf16(ah, Bl[cs][ks], acc[m][cs], 0,0,0);
          acc[m][cs] = __builtin_amdgcn_mfma_f32_16x16x32_bf16(al, Bh[cs][ks], acc[m][cs], 0,0,0);
          acc[m][cs] = __builtin_amdgcn_mfma_f32_16x16x32_bf16(al, Bl[cs][ks], acc[m][cs], 0,0,0);
        }
      }
    }
  }
  #pragma unroll
  for (int m = 0; m < 2; m++)
    #pragma unroll
    for (int cs = 0; cs < 4; cs++)
      #pragma unroll
      for (int r = 0; r < 4; r++)
        zlin[(size_t)(rb + wr*32 + m*16 + hi*4 + r)*DC + wc*64 + cs*16 + lo] = acc[m][cs][r];
}

// ---------------- Kernel 2b: row l2norm in-place + bf16 copy ----------------
__global__ __launch_bounds__(256) void k_norm(float* __restrict__ zn,
                                              unsigned short* __restrict__ zbf) {
  const int lane = threadIdx.x & 63;
  const int wv = threadIdx.x >> 6;
  const int row = blockIdx.x*4 + wv;
  float4 v = *reinterpret_cast<const float4*>(&zn[(size_t)row*DC + lane*4]);
  float s = v.x*v.x + v.y*v.y + v.z*v.z + v.w*v.w;
  #pragma unroll
  for (int m = 1; m < 64; m <<= 1) s += __shfl_xor(s, m);
  float inv = 1.0f / fmaxf(sqrtf(s), 1e-12f);
  v.x *= inv; v.y *= inv; v.z *= inv; v.w *= inv;
  *reinterpret_cast<float4*>(&zn[(size_t)row*DC + lane*4]) = v;
  ushort4 pk; pk.x = f2bf(v.x); pk.y = f2bf(v.y); pk.z = f2bf(v.z); pk.w = f2bf(v.w);
  *reinterpret_cast<ushort4*>(&zbf[(size_t)row*DC + lane*4]) = pk;
}

// ---------------- Kernel 3: MFMA distance passes ----------------
// 4 waves x 64 rows = 256 rows/block; grid (64, DSPLIT=8) = 512 blocks.
template<int PASS>
__global__ __launch_bounds__(256, 2) void k_dist(
    const unsigned short* __restrict__ zbf, const unsigned short* __restrict__ cbf,
    const float* __restrict__ zn, const float* __restrict__ cn,
    const float* __restrict__ c2, const float* __restrict__ rowbest,
    float* __restrict__ rbp, unsigned long long* __restrict__ keys) {
  __shared__ unsigned short Bs[64*256];   // 32 KB swizzled
  const int tid  = threadIdx.x;
  const int lane = tid & 63;
  const int wv   = tid >> 6;
  const int lo   = lane & 15, hi = lane >> 4;
  const int rbw  = blockIdx.x * 256 + wv * 64;
  const int cb0  = blockIdx.y * (KCB/DSPLIT);

  bf16x8 a[4][8];
  #pragma unroll
  for (int s = 0; s < 4; s++)
    #pragma unroll
    for (int ks = 0; ks < 8; ks++)
      a[s][ks] = *reinterpret_cast<const bf16x8*>(
          &zbf[(size_t)(rbw + s*16 + lo)*DC + ks*32 + hi*8]);

  float trk[4][4];
  #pragma unroll
  for (int s = 0; s < 4; s++)
    #pragma unroll
    for (int r = 0; r < 4; r++) {
      if (PASS == 1) trk[s][r] = -1e30f;
      else           trk[s][r] = rowbest[rbw + s*16 + hi*4 + r] - 0.01f;
    }

  int soff[8];
  #pragma unroll
  for (int i = 0; i < 8; i++) {
    int code = (wv*8 + i)*2 + (lane >> 5);
    int chg  = (lane & 31) ^ (code & 7);
    soff[i]  = code*512 + chg*16;
  }

  for (int t = 0; t < (KCB/DSPLIT)/64; t++) {
    const int cbx = cb0 + t*64;
    __syncthreads();
    #pragma unroll
    for (int i = 0; i < 8; i++)
      gload_lds16((const char*)cbf + (size_t)cbx*512 + soff[i], (char*)Bs + (wv*8 + i)*1024);
    asm volatile("s_waitcnt vmcnt(0)" ::: "memory");
    __syncthreads();

    f32x4 acc[4][4];
    #pragma unroll
    for (int s = 0; s < 4; s++)
      #pragma unroll
      for (int cs = 0; cs < 4; cs++) acc[s][cs] = (f32x4){0.f,0.f,0.f,0.f};

    #pragma unroll
    for (int ks = 0; ks < 8; ks++) {
      const int chl = (ks*4 + hi) ^ (lo & 7);
      bf16x8 b[4];
      #pragma unroll
      for (int cs = 0; cs < 4; cs++)
        b[cs] = *reinterpret_cast<const bf16x8*>(&Bs[(cs*16 + lo)*256 + chl*8]);
      #pragma unroll
      for (int cs = 0; cs < 4; cs++)
        #pragma unroll
        for (int s = 0; s < 4; s++)
          acc[s][cs] = __builtin_amdgcn_mfma_f32_16x16x32_bf16(a[s][ks], b[cs], acc[s][cs], 0,0,0);
    }

    if (PASS == 1) {
      #pragma unroll
      for (int s = 0; s < 4; s++)
        #pragma unroll
        for (int r = 0; r < 4; r++) {
          float mx = fmaxf(fmaxf(acc[s][0][r], acc[s][1][r]),
                           fmaxf(acc[s][2][r], acc[s][3][r]));
          trk[s][r] = fmaxf(trk[s][r], mx);
        }
    } else {
      #pragma unroll
      for (int s = 0; s < 4; s++)
        #pragma unroll
        for (int r = 0; r < 4; r++) {
          float mx = fmaxf(fmaxf(acc[s][0][r], acc[s][1][r]),
                           fmaxf(acc[s][2][r], acc[s][3][r]));
          if (mx >= trk[s][r]) {
            const int row = rbw + s*16 + hi*4 + r;
            #pragma unroll
            for (int cs = 0; cs < 4; cs++) {
              if (acc[s][cs][r] >= trk[s][r]) {
                const int code = cbx + cs*16 + lo;
                float dot = 0.f;
                const float4* zr = reinterpret_cast<const float4*>(zn + (size_t)row*DC);
                const float4* cr = reinterpret_cast<const float4*>(cn + (size_t)code*DC);
                #pragma unroll 4
                for (int q = 0; q < 64; q++) {
                  float4 x = zr[q], y = cr[q];
                  dot += x.x*y.x; dot += x.y*y.y; dot += x.z*y.z; dot += x.w*y.w;
                }
                float e = c2[code] - 2.f*dot;
                unsigned ue = __float_as_uint(e);
                ue = (ue & 0x80000000u) ? ~ue : (ue | 0x80000000u);
                unsigned long long key = ((unsigned long long)ue << 32) | (unsigned)code;
                atomicMin(&keys[row], key);
              }
            }
          }
        }
    }
  }

  if (PASS == 1) {
    #pragma unroll
    for (int s = 0; s < 4; s++)
      #pragma unroll
      for (int r = 0; r < 4; r++) {
        float m = trk[s][r];
        #pragma unroll
        for (int msk = 1; msk < 16; msk <<= 1) m = fmaxf(m, __shfl_xor(m, msk));
        if (lo == 0) rbp[(size_t)blockIdx.y*R_TOT + rbw + s*16 + hi*4 + r] = m;
      }
  }
}

__global__ __launch_bounds__(256) void k_combine(const float* __restrict__ rbp,
                                                 float* __restrict__ rowbest) {
  int r = blockIdx.x*256 + threadIdx.x;
  float m = rbp[r];
  #pragma unroll
  for (int p = 1; p < DSPLIT; p++) m = fmaxf(m, rbp[(size_t)p*R_TOT + r]);
  rowbest[r] = m;
}

__global__ __launch_bounds__(256) void k_final(const unsigned long long* __restrict__ keys,
                                               int* __restrict__ ci,
                                               float* __restrict__ cf) {
  int r = blockIdx.x*256 + threadIdx.x;
  int idx = (int)(keys[r] & 0xFFFFFFFFull);
  ci[r] = idx;
  cf[r] = (float)idx;
}

// ---------------- Kernel 4: q = gather(cbf) @ wqb^T via MFMA ----------------
// 4 waves x 64 rows; grid (64, 8): block = 256 rows x 128 d-cols; 2 tiles of 64 d.
__global__ __launch_bounds__(256, 2) void k_qgemm2(const int* __restrict__ ci,
                                                   const unsigned short* __restrict__ cbf,
                                                   const unsigned short* __restrict__ wqb,
                                                   float* __restrict__ qout) {
  __shared__ unsigned short Bs[64*256];
  const int tid  = threadIdx.x;
  const int lane = tid & 63;
  const int wv   = tid >> 6;
  const int lo   = lane & 15, hi = lane >> 4;
  const int rbw  = blockIdx.x * 256 + wv * 64;
  const int db   = blockIdx.y * 128;

  bf16x8 a[4][8];
  #pragma unroll
  for (int s = 0; s < 4; s++) {
    int code = ci[rbw + s*16 + lo];
    #pragma unroll
    for (int ks = 0; ks < 8; ks++)
      a[s][ks] = *reinterpret_cast<const bf16x8*>(&cbf[(size_t)code*DC + ks*32 + hi*8]);
  }

  int soff[8];
  #pragma unroll
  for (int i = 0; i < 8; i++) {
    int d = (wv*8 + i)*2 + (lane >> 5);
    int chg = (lane & 31) ^ (d & 7);
    soff[i] = d*512 + chg*16;
  }

  for (int t = 0; t < 2; t++) {
    const int dbx = db + t*64;
    __syncthreads();
    #pragma unroll
    for (int i = 0; i < 8; i++)
      gload_lds16((const char*)wqb + (size_t)dbx*512 + soff[i], (char*)Bs + (wv*8 + i)*1024);
    asm volatile("s_waitcnt vmcnt(0)" ::: "memory");
    __syncthreads();

    f32x4 acc[4][4];
    #pragma unroll
    for (int s = 0; s < 4; s++)
      #pragma unroll
      for (int cs = 0; cs < 4; cs++) acc[s][cs] = (f32x4){0.f,0.f,0.f,0.f};
    #pragma unroll
    for (int ks = 0; ks < 8; ks++) {
      const int chl = (ks*4 + hi) ^ (lo & 7);
      bf16x8 b[4];
      #pragma unroll
      for (int cs = 0; cs < 4; cs++)
        b[cs] = *reinterpret_cast<const bf16x8*>(&Bs[(cs*16 + lo)*256 + chl*8]);
      #pragma unroll
      for (int cs = 0; cs < 4; cs++)
        #pragma unroll
        for (int s = 0; s < 4; s++)
          acc[s][cs] = __builtin_amdgcn_mfma_f32_16x16x32_bf16(a[s][ks], b[cs], acc[s][cs], 0,0,0);
    }
    #pragma unroll
    for (int s = 0; s < 4; s++)
      #pragma unroll
      for (int cs = 0; cs < 4; cs++)
        #pragma unroll
        for (int r = 0; r < 4; r++)
          qout[(size_t)(rbw + s*16 + hi*4 + r)*DIN + dbx + cs*16 + lo] = acc[s][cs][r];
  }
}

// ---------------- Kernel 5/6: quantize loss ----------------
__global__ __launch_bounds__(256) void k_losspart(const float* __restrict__ zn,
                                                  const float* __restrict__ cn,
                                                  const int* __restrict__ codes_i,
                                                  float* __restrict__ part) {
  const int tid = threadIdx.x;
  const size_t base = (size_t)blockIdx.x * 8192;
  float s = 0.f;
  #pragma unroll
  for (int k = 0; k < 32; k++) {
    size_t e = base + (size_t)k*256 + tid;
    int r = (int)(e >> 8);
    int c = (int)(e & 255);
    float d = cn[(size_t)codes_i[r]*DC + c] - zn[e];
    s += d * d;
  }
  #pragma unroll
  for (int m = 1; m < 64; m <<= 1) s += __shfl_xor(s, m);
  __shared__ float red[4];
  if ((tid & 63) == 0) red[tid >> 6] = s;
  __syncthreads();
  if (tid == 0) part[blockIdx.x] = (red[0] + red[1]) + (red[2] + red[3]);
}

__global__ __launch_bounds__(256) void k_lossfinal(const float* __restrict__ part,
                                                   float* __restrict__ loss_out) {
  const int tid = threadIdx.x;
  float s = part[tid] + part[tid + 256];
  #pragma unroll
  for (int m = 1; m < 64; m <<= 1) s += __shfl_xor(s, m);
  __shared__ float red[4];
  if ((tid & 63) == 0) red[tid >> 6] = s;
  __syncthreads();
  if (tid == 0) {
    float tot = (red[0] + red[1]) + (red[2] + red[3]);
    loss_out[0] = tot * 1.25f / 4194304.0f;
  }
}

extern "C" void kernel_launch(void* const* d_in, const int* in_sizes, int n_in,
                              void* d_out, int out_size, void* d_ws, size_t ws_size,
                              hipStream_t stream) {
  const float* z  = (const float*)d_in[0];
  const float* cb = (const float*)d_in[1];
  const float* wz = (const float*)d_in[2];
  const float* wq = (const float*)d_in[3];

  float* out = (float*)d_out;
  float* q_out   = out;
  float* codes_f = out + (size_t)R_TOT*DIN;
  float* loss_o  = codes_f + R_TOT;

  float* ws = (float*)d_ws;
  float* cn = ws + WS_CN;
  float* zn = ws + WS_ZN;
  float* c2 = ws + WS_C2;
  int*   ci = (int*)(ws + WS_CODES);
  float* pt = ws + WS_PART;
  unsigned short* cbf = (unsigned short*)(ws + WS_CBF);
  unsigned short* zbf = (unsigned short*)(ws + WS_ZBF);
  float* rbp = ws + WS_RBP;
  float* rb  = ws + WS_RB;
  unsigned long long* keys = (unsigned long long*)(ws + WS_KEYS);
  unsigned short* wh  = (unsigned short*)(ws + WS_WH);
  unsigned short* wl  = (unsigned short*)(ws + WS_WL);
  unsigned short* wqb = (unsigned short*)(ws + WS_WQB);

  hipMemsetAsync(keys, 0xFF, (size_t)R_TOT*sizeof(unsigned long long), stream);
  hipLaunchKernelGGL(k_codenorm, dim3(KCB), dim3(64), 0, stream, cb, cn, c2, cbf);
  hipLaunchKernelGGL(k_wprep, dim3(1024), dim3(256), 0, stream, wz, wq, wh, wl, wqb);
  hipLaunchKernelGGL(k_zlin2, dim3(R_TOT/64), dim3(512), 0, stream, z, wh, wl, zn);
  hipLaunchKernelGGL(k_norm, dim3(R_TOT/4), dim3(256), 0, stream, zn, zbf);
  hipLaunchKernelGGL((k_dist<1>), dim3(R_TOT/256, DSPLIT), dim3(256), 0, stream,
                     zbf, cbf, zn, cn, c2, rb, rbp, keys);
  hipLaunchKernelGGL(k_combine, dim3(R_TOT/256), dim3(256), 0, stream, rbp, rb);
  hipLaunchKernelGGL((k_dist<2>), dim3(R_TOT/256, DSPLIT), dim3(256), 0, stream,
                     zbf, cbf, zn, cn, c2, rb, rbp, keys);
  hipLaunchKernelGGL(k_final, dim3(R_TOT/256), dim3(256), 0, stream, keys, ci, codes_f);
  hipLaunchKernelGGL(k_qgemm2, dim3(R_TOT/256, DIN/128), dim3(256), 0, stream, ci, cbf, wqb, q_out);
  hipLaunchKernelGGL(k_losspart, dim3(512), dim3(256), 0, stream, zn, cn, ci, pt);
  hipLaunchKernelGGL(k_lossfinal, dim3(1), dim3(256), 0, stream, pt, loss_o);
}